// Round 1
// baseline (256.770 us; speedup 1.0000x reference)
//
#include <hip/hip_runtime.h>
#include <hip/hip_bf16.h>

#define T_TOK 2048
#define E_DIM 1024
#define F_DIM 2048
#define N_EXP 8

typedef __attribute__((ext_vector_type(8))) short short8;
typedef __attribute__((ext_vector_type(4))) float f32x4;

__device__ __forceinline__ short bf2s(__hip_bfloat16 v) {
  union { __hip_bfloat16 b; short s; } u; u.b = v; return u.s;
}

__device__ __forceinline__ void gload_lds16(const void* g, void* l) {
  __builtin_amdgcn_global_load_lds((const __attribute__((address_space(1))) void*)g,
                                   (__attribute__((address_space(3))) void*)l, 16, 0, 0);
}

// ---------------- x fp32 -> bf16 ----------------
__global__ __launch_bounds__(256) void convert_x_kernel(const float* __restrict__ x,
                                                        __hip_bfloat16* __restrict__ xb) {
  size_t i = ((size_t)blockIdx.x * 256 + threadIdx.x) * 8;
  float4 a = *(const float4*)(x + i);
  float4 b = *(const float4*)(x + i + 4);
  short8 o;
  o[0] = bf2s(__float2bfloat16(a.x)); o[1] = bf2s(__float2bfloat16(a.y));
  o[2] = bf2s(__float2bfloat16(a.z)); o[3] = bf2s(__float2bfloat16(a.w));
  o[4] = bf2s(__float2bfloat16(b.x)); o[5] = bf2s(__float2bfloat16(b.y));
  o[6] = bf2s(__float2bfloat16(b.z)); o[7] = bf2s(__float2bfloat16(b.w));
  *(short8*)(xb + i) = o;
}

// ------------- transpose+convert: src fp32 [R][C] -> dst bf16 [C][R], batched over z -------------
template <int R, int C>
__global__ __launch_bounds__(256) void transpose_convert_kernel(const float* __restrict__ src,
                                                                __hip_bfloat16* __restrict__ dst) {
  __shared__ __hip_bfloat16 lt[64][72];
  size_t bo = (size_t)blockIdx.z * R * C;
  int r0 = blockIdx.y * 64, c0 = blockIdx.x * 64;
  int tid = threadIdx.x;
#pragma unroll
  for (int i = 0; i < 4; i++) {
    int chunk = i * 256 + tid;
    int r = chunk >> 4, c4 = (chunk & 15) * 4;
    float4 v = *(const float4*)(src + bo + (size_t)(r0 + r) * C + c0 + c4);
    lt[r][c4 + 0] = __float2bfloat16(v.x);
    lt[r][c4 + 1] = __float2bfloat16(v.y);
    lt[r][c4 + 2] = __float2bfloat16(v.z);
    lt[r][c4 + 3] = __float2bfloat16(v.w);
  }
  __syncthreads();
#pragma unroll
  for (int i = 0; i < 2; i++) {
    int chunk = i * 256 + tid;
    int c = chunk >> 3, rr = (chunk & 7) * 8;
    short8 o;
#pragma unroll
    for (int j = 0; j < 8; j++) o[j] = bf2s(lt[rr + j][c]);
    *(short8*)(dst + bo + (size_t)(c0 + c) * R + r0 + rr) = o;
  }
}

// ---------------- router: fp64 logits, top-2, softmax ----------------
__global__ __launch_bounds__(256) void router_kernel(const float* __restrict__ x,
                                                     const float* __restrict__ gk,
                                                     int* __restrict__ tk_e,
                                                     float* __restrict__ tk_p,
                                                     int* __restrict__ counts) {
  int w = threadIdx.x >> 6, l = threadIdx.x & 63;
  int t = blockIdx.x * 4 + w;
  const float* xr = x + (size_t)t * E_DIM;
  double acc[N_EXP];
#pragma unroll
  for (int n = 0; n < N_EXP; n++) acc[n] = 0.0;
  for (int j = 0; j < 16; j++) {
    int i = j * 64 + l;
    double xv = (double)xr[i];
    const float* g = gk + (size_t)i * N_EXP;
#pragma unroll
    for (int n = 0; n < N_EXP; n++) acc[n] += xv * (double)g[n];
  }
#pragma unroll
  for (int off = 32; off > 0; off >>= 1) {
#pragma unroll
    for (int n = 0; n < N_EXP; n++) acc[n] += __shfl_down(acc[n], off);
  }
  if (l == 0) {
    int e1 = 0; double v1 = acc[0];
    for (int n = 1; n < N_EXP; n++) if (acc[n] > v1) { v1 = acc[n]; e1 = n; }
    int e2 = -1; double v2 = -1e300;
    for (int n = 0; n < N_EXP; n++) if (n != e1 && acc[n] > v2) { v2 = acc[n]; e2 = n; }
    float ex = __expf((float)(v2 - v1));     // <= 1
    float p1 = 1.f / (1.f + ex);
    float p2 = ex / (1.f + ex);
    tk_e[t * 2 + 0] = e1; tk_p[t * 2 + 0] = p1;
    tk_e[t * 2 + 1] = e2; tk_p[t * 2 + 1] = p2;
    atomicAdd(&counts[e1], 1);
    atomicAdd(&counts[e2], 1);
  }
}

// ---------------- scan: offsets + m-tile table ----------------
// ctrl layout (ints): [0..7] counts, [8..15] cursors, [16..23] offs, [24] ntiles,
//                     [32..95] tbl_e, [96..159] tbl_slot0, [160..223] tbl_rows
__global__ void scan_kernel(int* ctrl) {
  if (threadIdx.x != 0) return;
  int off = 0, idx = 0;
  for (int e = 0; e < N_EXP; e++) {
    ctrl[16 + e] = off;
    int c = ctrl[e];
    for (int m0 = 0; m0 < c; m0 += 128) {
      ctrl[32 + idx] = e;
      ctrl[96 + idx] = off + m0;
      ctrl[160 + idx] = (c - m0 < 128) ? (c - m0) : 128;
      idx++;
    }
    off += c;
  }
  ctrl[24] = idx;
}

// ---------------- permute: build slot lists ----------------
__global__ __launch_bounds__(256) void permute_kernel(const int* __restrict__ tk_e,
                                                      const float* __restrict__ tk_p,
                                                      int* __restrict__ ctrl,
                                                      int* __restrict__ slot_tok,
                                                      float* __restrict__ slot_prob) {
  int g = blockIdx.x * 256 + threadIdx.x;   // 0..4095
  int e = tk_e[g];
  float p = tk_p[g];
  int pos = atomicAdd(&ctrl[8 + e], 1);
  int slot = ctrl[16 + e] + pos;
  slot_tok[slot] = g >> 1;
  slot_prob[slot] = p;
}

// ---------------- GEMM1: h = silu(X@w0) * (X@w1), grouped, bf16 MFMA ----------------
// block tile: 128 rows (tokens) x 64 cols (F), BK=64; 4 waves, each 32x64.
__global__ __launch_bounds__(256) void gemm1_kernel(const __hip_bfloat16* __restrict__ xb,
                                                    const __hip_bfloat16* __restrict__ w0t,
                                                    const __hip_bfloat16* __restrict__ w1t,
                                                    const int* __restrict__ ctrl,
                                                    const int* __restrict__ slot_tok,
                                                    __hip_bfloat16* __restrict__ h) {
  if ((int)blockIdx.x >= ctrl[24]) return;
  int e = ctrl[32 + blockIdx.x];
  int slot0 = ctrl[96 + blockIdx.x];
  int rowsv = ctrl[160 + blockIdx.x];
  int n0 = blockIdx.y * 64;

  __shared__ alignas(16) __hip_bfloat16 lA[128 * 64];
  __shared__ alignas(16) __hip_bfloat16 lB0[64 * 64];
  __shared__ alignas(16) __hip_bfloat16 lB1[64 * 64];

  int tid = threadIdx.x;
  int w = tid >> 6, l = tid & 63;
  int rA = tid >> 3;                  // staging row base
  int kcA = (tid & 7) ^ (rA & 7);     // swizzled k-chunk
  int frow = l & 15, fk = l >> 4;

  int tok[4];
#pragma unroll
  for (int c = 0; c < 4; c++) tok[c] = slot_tok[slot0 + rA + 32 * c];

  const __hip_bfloat16* b0base = w0t + ((size_t)e * F_DIM + n0) * E_DIM;
  const __hip_bfloat16* b1base = w1t + ((size_t)e * F_DIM + n0) * E_DIM;

  f32x4 zero4 = {0.f, 0.f, 0.f, 0.f};
  f32x4 acc0[2][4], acc1[2][4];
#pragma unroll
  for (int mi = 0; mi < 2; mi++)
#pragma unroll
    for (int ni = 0; ni < 4; ni++) { acc0[mi][ni] = zero4; acc1[mi][ni] = zero4; }

  for (int k0 = 0; k0 < E_DIM; k0 += 64) {
    __syncthreads();
#pragma unroll
    for (int c = 0; c < 4; c++)
      gload_lds16(xb + (size_t)tok[c] * E_DIM + k0 + kcA * 8, &lA[(c * 256 + w * 64) * 8]);
#pragma unroll
    for (int c = 0; c < 2; c++)
      gload_lds16(b0base + (size_t)(rA + 32 * c) * E_DIM + k0 + kcA * 8, &lB0[(c * 256 + w * 64) * 8]);
#pragma unroll
    for (int c = 0; c < 2; c++)
      gload_lds16(b1base + (size_t)(rA + 32 * c) * E_DIM + k0 + kcA * 8, &lB1[(c * 256 + w * 64) * 8]);
    __syncthreads();

#pragma unroll
    for (int ks = 0; ks < 2; ks++) {
      int kc = (((ks * 4) + fk) ^ (l & 7)) * 8;
      short8 a[2], b0[4], b1[4];
#pragma unroll
      for (int mi = 0; mi < 2; mi++)
        a[mi] = *(const short8*)&lA[(w * 32 + mi * 16 + frow) * 64 + kc];
#pragma unroll
      for (int ni = 0; ni < 4; ni++) {
        b0[ni] = *(const short8*)&lB0[(ni * 16 + frow) * 64 + kc];
        b1[ni] = *(const short8*)&lB1[(ni * 16 + frow) * 64 + kc];
      }
#pragma unroll
      for (int mi = 0; mi < 2; mi++)
#pragma unroll
        for (int ni = 0; ni < 4; ni++) {
          acc0[mi][ni] = __builtin_amdgcn_mfma_f32_16x16x32_bf16(a[mi], b0[ni], acc0[mi][ni], 0, 0, 0);
          acc1[mi][ni] = __builtin_amdgcn_mfma_f32_16x16x32_bf16(a[mi], b1[ni], acc1[mi][ni], 0, 0, 0);
        }
    }
  }

#pragma unroll
  for (int mi = 0; mi < 2; mi++) {
#pragma unroll
    for (int j = 0; j < 4; j++) {
      int row = w * 32 + mi * 16 + fk * 4 + j;
      if (row < rowsv) {
        __hip_bfloat16* hr = h + (size_t)(slot0 + row) * F_DIM + n0;
#pragma unroll
        for (int ni = 0; ni < 4; ni++) {
          float v0 = acc0[mi][ni][j];
          float v1 = acc1[mi][ni][j];
          float s = (v0 / (1.f + __expf(-v0))) * v1;   // silu(v0)*v1
          hr[ni * 16 + frow] = __float2bfloat16(s);
        }
      }
    }
  }
}

// ---------------- GEMM2: out += p * (h @ wo), grouped, scatter-add ----------------
__global__ __launch_bounds__(256) void gemm2_kernel(const __hip_bfloat16* __restrict__ h,
                                                    const __hip_bfloat16* __restrict__ wot,
                                                    const int* __restrict__ ctrl,
                                                    const int* __restrict__ slot_tok,
                                                    const float* __restrict__ slot_prob,
                                                    float* __restrict__ out) {
  if ((int)blockIdx.x >= ctrl[24]) return;
  int e = ctrl[32 + blockIdx.x];
  int slot0 = ctrl[96 + blockIdx.x];
  int rowsv = ctrl[160 + blockIdx.x];
  int n0 = blockIdx.y * 64;

  __shared__ alignas(16) __hip_bfloat16 lA[128 * 64];
  __shared__ alignas(16) __hip_bfloat16 lB[64 * 64];

  int tid = threadIdx.x;
  int w = tid >> 6, l = tid & 63;
  int rA = tid >> 3;
  int kcA = (tid & 7) ^ (rA & 7);
  int frow = l & 15, fk = l >> 4;

  const __hip_bfloat16* abase = h + (size_t)slot0 * F_DIM;
  const __hip_bfloat16* bbase = wot + ((size_t)e * E_DIM + n0) * F_DIM;

  f32x4 zero4 = {0.f, 0.f, 0.f, 0.f};
  f32x4 acc[2][4];
#pragma unroll
  for (int mi = 0; mi < 2; mi++)
#pragma unroll
    for (int ni = 0; ni < 4; ni++) acc[mi][ni] = zero4;

  for (int k0 = 0; k0 < F_DIM; k0 += 64) {
    __syncthreads();
#pragma unroll
    for (int c = 0; c < 4; c++)
      gload_lds16(abase + (size_t)(rA + 32 * c) * F_DIM + k0 + kcA * 8, &lA[(c * 256 + w * 64) * 8]);
#pragma unroll
    for (int c = 0; c < 2; c++)
      gload_lds16(bbase + (size_t)(rA + 32 * c) * F_DIM + k0 + kcA * 8, &lB[(c * 256 + w * 64) * 8]);
    __syncthreads();

#pragma unroll
    for (int ks = 0; ks < 2; ks++) {
      int kc = (((ks * 4) + fk) ^ (l & 7)) * 8;
      short8 a[2], b[4];
#pragma unroll
      for (int mi = 0; mi < 2; mi++)
        a[mi] = *(const short8*)&lA[(w * 32 + mi * 16 + frow) * 64 + kc];
#pragma unroll
      for (int ni = 0; ni < 4; ni++)
        b[ni] = *(const short8*)&lB[(ni * 16 + frow) * 64 + kc];
#pragma unroll
      for (int mi = 0; mi < 2; mi++)
#pragma unroll
        for (int ni = 0; ni < 4; ni++)
          acc[mi][ni] = __builtin_amdgcn_mfma_f32_16x16x32_bf16(a[mi], b[ni], acc[mi][ni], 0, 0, 0);
    }
  }

#pragma unroll
  for (int mi = 0; mi < 2; mi++) {
#pragma unroll
    for (int j = 0; j < 4; j++) {
      int row = w * 32 + mi * 16 + fk * 4 + j;
      if (row < rowsv) {
        int slot = slot0 + row;
        int t = slot_tok[slot];
        float p = slot_prob[slot];
        float* orow = out + (size_t)t * E_DIM + n0;
#pragma unroll
        for (int ni = 0; ni < 4; ni++)
          atomicAdd(&orow[ni * 16 + frow], p * acc[mi][ni][j]);
      }
    }
  }
}

extern "C" void kernel_launch(void* const* d_in, const int* in_sizes, int n_in,
                              void* d_out, int out_size, void* d_ws, size_t ws_size,
                              hipStream_t stream) {
  const float* x  = (const float*)d_in[0];
  const float* gk = (const float*)d_in[1];
  const float* w0 = (const float*)d_in[2];
  const float* w1 = (const float*)d_in[3];
  const float* wo = (const float*)d_in[4];
  float* out = (float*)d_out;
  char* ws = (char*)d_ws;

  const size_t OFF_XB   = 0;
  const size_t OFF_W0T  = OFF_XB  + (size_t)T_TOK * E_DIM * 2;
  const size_t OFF_W1T  = OFF_W0T + (size_t)N_EXP * E_DIM * F_DIM * 2;
  const size_t OFF_WOT  = OFF_W1T + (size_t)N_EXP * E_DIM * F_DIM * 2;
  const size_t OFF_H    = OFF_WOT + (size_t)N_EXP * F_DIM * E_DIM * 2;
  const size_t OFF_STOK = OFF_H   + (size_t)(4096 + 128) * F_DIM * 2;
  const size_t OFF_SPRB = OFF_STOK + (size_t)(4096 + 128) * 4;
  const size_t OFF_TKE  = OFF_SPRB + (size_t)(4096 + 128) * 4;
  const size_t OFF_TKP  = OFF_TKE + 4096 * 4;
  const size_t OFF_CTRL = OFF_TKP + 4096 * 4;
  const size_t NEED     = OFF_CTRL + 1024;
  if (ws_size < NEED) return;   // visible failure rather than corruption

  __hip_bfloat16* xb   = (__hip_bfloat16*)(ws + OFF_XB);
  __hip_bfloat16* w0t  = (__hip_bfloat16*)(ws + OFF_W0T);
  __hip_bfloat16* w1t  = (__hip_bfloat16*)(ws + OFF_W1T);
  __hip_bfloat16* wot  = (__hip_bfloat16*)(ws + OFF_WOT);
  __hip_bfloat16* hbuf = (__hip_bfloat16*)(ws + OFF_H);
  int*   slot_tok  = (int*)(ws + OFF_STOK);
  float* slot_prob = (float*)(ws + OFF_SPRB);
  int*   tk_e      = (int*)(ws + OFF_TKE);
  float* tk_p      = (float*)(ws + OFF_TKP);
  int*   ctrl      = (int*)(ws + OFF_CTRL);

  hipMemsetAsync(d_out, 0, (size_t)out_size * 4, stream);
  hipMemsetAsync(ctrl, 0, 1024, stream);
  hipMemsetAsync(slot_tok + 4096, 0, 128 * 4, stream);   // pad rows -> token 0

  convert_x_kernel<<<(T_TOK * E_DIM) / (256 * 8), 256, 0, stream>>>(x, xb);
  transpose_convert_kernel<E_DIM, F_DIM><<<dim3(F_DIM / 64, E_DIM / 64, N_EXP), 256, 0, stream>>>(w0, w0t);
  transpose_convert_kernel<E_DIM, F_DIM><<<dim3(F_DIM / 64, E_DIM / 64, N_EXP), 256, 0, stream>>>(w1, w1t);
  transpose_convert_kernel<F_DIM, E_DIM><<<dim3(E_DIM / 64, F_DIM / 64, N_EXP), 256, 0, stream>>>(wo, wot);
  router_kernel<<<T_TOK / 4, 256, 0, stream>>>(x, gk, tk_e, tk_p, ctrl);
  scan_kernel<<<1, 64, 0, stream>>>(ctrl);
  permute_kernel<<<4096 / 256, 256, 0, stream>>>(tk_e, tk_p, ctrl, slot_tok, slot_prob);
  gemm1_kernel<<<dim3(40, F_DIM / 64), 256, 0, stream>>>(xb, w0t, w1t, ctrl, slot_tok, hbuf);
  gemm2_kernel<<<dim3(40, E_DIM / 64), 256, 0, stream>>>(hbuf, wot, ctrl, slot_tok, slot_prob, out);
}